// Round 1
// baseline (1417.858 us; speedup 1.0000x reference)
//
#include <hip/hip_runtime.h>
#include <hip/hip_fp16.h>

#define B_   32
#define T_   256
#define D_   1024
#define H_   8
#define DH_  128
#define HID_ 256

typedef unsigned short u16;
typedef __attribute__((ext_vector_type(8))) short  s16x8;
typedef __attribute__((ext_vector_type(8))) __bf16 bf16x8;
typedef __attribute__((ext_vector_type(4))) float  f32x4;
typedef __attribute__((ext_vector_type(2))) _Float16 h2v;

__device__ __forceinline__ u16 f2bf(float f){
  union { float f; unsigned u; } v; v.f = f;
  unsigned r = v.u + 0x7FFFu + ((v.u >> 16) & 1u);   // RNE
  return (u16)(r >> 16);
}

__device__ __forceinline__ f32x4 mfma_bf16(s16x8 a, s16x8 b, f32x4 c){
  bf16x8 av, bv;
  __builtin_memcpy(&av, &a, 16);
  __builtin_memcpy(&bv, &b, 16);
  return __builtin_amdgcn_mfma_f32_16x16x32_bf16(av, bv, c, 0, 0, 0);
}

#if defined(__has_builtin)
#if __has_builtin(__builtin_amdgcn_fdot2)
#define HAVE_FDOT2 1
#endif
#endif

__device__ __forceinline__ float fdot2f(__half2 a, __half2 b, float c){
#ifdef HAVE_FDOT2
  h2v av, bv;
  __builtin_memcpy(&av, &a, 4);
  __builtin_memcpy(&bv, &b, 4);
  return __builtin_amdgcn_fdot2(av, bv, c, false);
#else
  return c + __low2float(a)*__low2float(b) + __high2float(a)*__high2float(b);
#endif
}

// ---------------- h = x[:, :, :1024] ----------------
__global__ void k_copy_h(const float* __restrict__ x, float* __restrict__ h){
  int m = blockIdx.x;
  int c = threadIdx.x * 4;
  *(float4*)&h[(size_t)m*D_ + c] = *(const float4*)&x[(size_t)m*2560 + c];
}

// ---------------- transpose K x N fp32 -> N x K bf16 ----------------
__global__ void k_transpose_bf16(const float* __restrict__ in, u16* __restrict__ out,
                                 int K, int N){
  __shared__ u16 tile[64][65];
  int kb = blockIdx.y * 64, nb = blockIdx.x * 64;
  int tid = threadIdx.x;
  {
    int k  = tid >> 2;
    int n0 = (tid & 3) * 16;
    const float* ip = in + (size_t)(kb + k) * N + nb + n0;
    #pragma unroll
    for (int i = 0; i < 4; ++i){
      float4 v = *(const float4*)(ip + i*4);
      tile[k][n0 + i*4 + 0] = f2bf(v.x);
      tile[k][n0 + i*4 + 1] = f2bf(v.y);
      tile[k][n0 + i*4 + 2] = f2bf(v.z);
      tile[k][n0 + i*4 + 3] = f2bf(v.w);
    }
  }
  __syncthreads();
  {
    int n  = tid >> 2;
    int k0 = (tid & 3) * 16;
    union { u16 u[16]; uint4 v[2]; } p;
    #pragma unroll
    for (int i = 0; i < 16; ++i) p.u[i] = tile[k0 + i][n];
    uint4* op = (uint4*)(out + (size_t)(nb + n) * K + kb + k0);
    op[0] = p.v[0]; op[1] = p.v[1];
  }
}

__global__ void k_f32_to_bf16(const float* __restrict__ in, u16* __restrict__ out, int n){
  int i = blockIdx.x * blockDim.x + threadIdx.x;
  if (i < n) out[i] = f2bf(in[i]);
}
__global__ void k_f32_to_f16(const float* __restrict__ in, __half* __restrict__ out, int n){
  int i = blockIdx.x * blockDim.x + threadIdx.x;
  if (i < n) out[i] = __float2half(in[i]);
}

__global__ void k_lengths(const int* __restrict__ mask, int* __restrict__ len){
  int b = blockIdx.x;
  int v = mask[b * T_ + threadIdx.x];
  #pragma unroll
  for (int off = 1; off < 64; off <<= 1) v += __shfl_xor(v, off);
  __shared__ int s[4];
  if ((threadIdx.x & 63) == 0) s[threadIdx.x >> 6] = v;
  __syncthreads();
  if (threadIdx.x == 0) len[b] = s[0] + s[1] + s[2] + s[3];
}

// ---------------- GEMM: out[M,N] = A[M,K](fp32, lda) @ Wb[N,K](bf16)^T + bias (+res) ----
// 128x128 tile, BK=32, 256 threads (4 waves, 2x2, each 64x64), mfma 16x16x32 bf16.
template<bool RES>
__global__ __launch_bounds__(256, 2)
void k_gemm(const float* __restrict__ A, int lda,
            const u16* __restrict__ Wb,
            const float* __restrict__ bias,
            const float* res,
            float* out,
            int K, int N)
{
  __shared__ __align__(16) short As[4*128*8];  // [kb][row][8]
  __shared__ __align__(16) short Bs[4*128*8];  // [kb][n][8]
  int tid = threadIdx.x;
  int n0 = blockIdx.x * 128, m0 = blockIdx.y * 128;
  int lane = tid & 63, w = tid >> 6;
  int wm = w >> 1, wn = w & 1;
  int lrow = lane & 15, lq = lane >> 4;
  f32x4 acc[4][4] = {};

  int srow = tid >> 1, skh = tid & 1;
  const float* aBase = A  + (size_t)(m0 + srow) * lda + skh * 16;
  const u16*   bBase = Wb + (size_t)(n0 + srow) * K   + skh * 16;
  short* aDst0 = &As[((skh*2 + 0)*128 + srow) * 8];
  short* aDst1 = &As[((skh*2 + 1)*128 + srow) * 8];
  short* bDst0 = &Bs[((skh*2 + 0)*128 + srow) * 8];
  short* bDst1 = &Bs[((skh*2 + 1)*128 + srow) * 8];

  for (int k0 = 0; k0 < K; k0 += 32){
    const float* ap = aBase + k0;
    float4 a0 = *(const float4*)(ap + 0);
    float4 a1 = *(const float4*)(ap + 4);
    float4 a2 = *(const float4*)(ap + 8);
    float4 a3 = *(const float4*)(ap + 12);
    const uint4* bp = (const uint4*)(bBase + k0);
    uint4 bv0 = bp[0], bv1 = bp[1];
    union { u16 u[8]; uint4 v; } p0, p1;
    p0.u[0]=f2bf(a0.x); p0.u[1]=f2bf(a0.y); p0.u[2]=f2bf(a0.z); p0.u[3]=f2bf(a0.w);
    p0.u[4]=f2bf(a1.x); p0.u[5]=f2bf(a1.y); p0.u[6]=f2bf(a1.z); p0.u[7]=f2bf(a1.w);
    p1.u[0]=f2bf(a2.x); p1.u[1]=f2bf(a2.y); p1.u[2]=f2bf(a2.z); p1.u[3]=f2bf(a2.w);
    p1.u[4]=f2bf(a3.x); p1.u[5]=f2bf(a3.y); p1.u[6]=f2bf(a3.z); p1.u[7]=f2bf(a3.w);
    *(uint4*)aDst0 = p0.v;
    *(uint4*)aDst1 = p1.v;
    *(uint4*)bDst0 = bv0;
    *(uint4*)bDst1 = bv1;
    __syncthreads();

    s16x8 af[4], bfr[4];
    #pragma unroll
    for (int mt = 0; mt < 4; ++mt)
      af[mt] = *(const s16x8*)&As[(lq*128 + wm*64 + mt*16 + lrow) * 8];
    #pragma unroll
    for (int nt = 0; nt < 4; ++nt)
      bfr[nt] = *(const s16x8*)&Bs[(lq*128 + wn*64 + nt*16 + lrow) * 8];
    #pragma unroll
    for (int mt = 0; mt < 4; ++mt)
      #pragma unroll
      for (int nt = 0; nt < 4; ++nt)
        acc[mt][nt] = mfma_bf16(af[mt], bfr[nt], acc[mt][nt]);
    __syncthreads();
  }

  #pragma unroll
  for (int mt = 0; mt < 4; ++mt){
    int rowb = m0 + wm*64 + mt*16 + lq*4;
    #pragma unroll
    for (int nt = 0; nt < 4; ++nt){
      int col = n0 + wn*64 + nt*16 + lrow;
      float bcol = bias[col];
      f32x4 a = acc[mt][nt];
      #pragma unroll
      for (int r = 0; r < 4; ++r){
        size_t idx = (size_t)(rowb + r) * N + col;
        float v = a[r] + bcol;
        if (RES) v += res[idx];
        out[idx] = v;
      }
    }
  }
}

// ---------------- banded attention (window +-3), one wave per (b,h,t) ----------------
__global__ void k_attn(const float* __restrict__ q, const float* __restrict__ kk,
                       const float* __restrict__ vv, float* ao){
  int bid = blockIdx.x;
  int lane = threadIdx.x;           // 64
  int t = bid & 255;
  int hh = (bid >> 8) & 7;
  int b = bid >> 11;
  size_t base = (((size_t)b*T_ + t)*H_ + hh)*DH_;
  float2 q2 = *(const float2*)&q[base + lane*2];
  int jlo = t - 3; if (jlo < 0) jlo = 0;
  int jhi = t + 3; if (jhi > T_ - 1) jhi = T_ - 1;
  const float scale = 0.08838834764831845f;   // 1/sqrt(128)
  float m = -1e30f, sum = 0.f;
  float2 o2; o2.x = 0.f; o2.y = 0.f;
  for (int j = jlo; j <= jhi; ++j){
    size_t kb = (((size_t)b*T_ + j)*H_ + hh)*DH_;
    float2 k2 = *(const float2*)&kk[kb + lane*2];
    float s = q2.x*k2.x + q2.y*k2.y;
    s += __shfl_xor(s, 1);  s += __shfl_xor(s, 2);  s += __shfl_xor(s, 4);
    s += __shfl_xor(s, 8);  s += __shfl_xor(s, 16); s += __shfl_xor(s, 32);
    float f  = s * scale;
    float nm = fmaxf(m, f);
    float c  = __expf(m - nm);
    float p  = __expf(f - nm);
    float2 v2 = *(const float2*)&vv[kb + lane*2];
    sum = sum*c + p;
    o2.x = o2.x*c + p*v2.x;
    o2.y = o2.y*c + p*v2.y;
    m = nm;
  }
  float inv = 1.f / sum;
  float2 r; r.x = o2.x*inv; r.y = o2.y*inv;
  *(float2*)&ao[base + lane*2] = r;
}

// ---------------- GRU scan: one block per (dir, batch); W_hh in registers (f16) -------
__global__ __launch_bounds__(512, 2)
void k_gru(const __half* __restrict__ WhhF, const __half* __restrict__ WhhB,
           const float* __restrict__ bhhF, const float* __restrict__ bhhB,
           const float* __restrict__ gxF, const float* __restrict__ gxB,
           const int* __restrict__ lengths, float* out)
{
  int dir = blockIdx.x >> 5, b = blockIdx.x & 31;
  const __half* Whh = dir ? WhhB : WhhF;
  const float*  bhh = dir ? bhhB : bhhF;
  const float*  gx  = dir ? gxB  : gxF;
  int tid = threadIdx.x;
  int j = tid >> 1, kc = tid & 1;        // pair (kc 0/1) are adjacent lanes in a wave

  // rows j (r), 256+j (z), 512+j (n); this thread's half of K: [kc*128, kc*128+128)
  __half2 w0[64], w1[64], w2[64];
  {
    const float4* p0 = (const float4*)(Whh + (size_t)j*256        + kc*128);
    const float4* p1 = (const float4*)(Whh + (size_t)(256+j)*256  + kc*128);
    const float4* p2 = (const float4*)(Whh + (size_t)(512+j)*256  + kc*128);
    #pragma unroll
    for (int c = 0; c < 16; ++c){
      union { float4 f; __half2 h[4]; } u;
      u.f = p0[c];
      w0[c*4+0]=u.h[0]; w0[c*4+1]=u.h[1]; w0[c*4+2]=u.h[2]; w0[c*4+3]=u.h[3];
      u.f = p1[c];
      w1[c*4+0]=u.h[0]; w1[c*4+1]=u.h[1]; w1[c*4+2]=u.h[2]; w1[c*4+3]=u.h[3];
      u.f = p2[c];
      w2[c*4+0]=u.h[0]; w2[c*4+1]=u.h[1]; w2[c*4+2]=u.h[2]; w2[c*4+3]=u.h[3];
    }
  }
  float bb0 = bhh[j], bb1 = bhh[256+j], bb2 = bhh[512+j];

  __shared__ __align__(16) __half hc[256];
  if (tid < 256) hc[tid] = __float2half(0.f);
  int len = lengths[b];
  if (tid < 256){
    for (int t = len; t < T_; ++t)
      out[((size_t)b*T_ + t)*512 + dir*256 + tid] = 0.f;
  }
  float hprev = 0.f;
  __syncthreads();

  for (int s = 0; s < len; ++s){
    int tt = dir ? (len - 1 - s) : s;
    float aR = 0.f, aZ = 0.f, aN = 0.f;
    const float4* hv4 = (const float4*)hc + kc*16;
    #pragma unroll
    for (int c = 0; c < 16; ++c){
      union { float4 f; __half2 h[4]; } u;
      u.f = hv4[c];
      #pragma unroll
      for (int i = 0; i < 4; ++i){
        aR = fdot2f(w0[c*4+i], u.h[i], aR);
        aZ = fdot2f(w1[c*4+i], u.h[i], aZ);
        aN = fdot2f(w2[c*4+i], u.h[i], aN);
      }
    }
    aR += __shfl_xor(aR, 1);
    aZ += __shfl_xor(aZ, 1);
    aN += __shfl_xor(aN, 1);
    __syncthreads();                     // all reads of hc for this step done
    if (kc == 0){
      size_t gb = ((size_t)b*T_ + tt)*768 + j;
      float r = 1.f / (1.f + __expf(-(gx[gb]       + aR + bb0)));
      float z = 1.f / (1.f + __expf(-(gx[gb + 256] + aZ + bb1)));
      float n = tanhf(gx[gb + 512] + r*(aN + bb2));
      float hnew = (1.f - z)*n + z*hprev;
      hprev = hnew;
      out[((size_t)b*T_ + tt)*512 + dir*256 + j] = hnew;
      hc[j] = __float2half(hnew);
    }
    __syncthreads();
  }
}

extern "C" void kernel_launch(void* const* d_in, const int* in_sizes, int n_in,
                              void* d_out, int out_size, void* d_ws, size_t ws_size,
                              hipStream_t stream)
{
  const float* x     = (const float*)d_in[0];
  const int*   mask  = (const int*)  d_in[1];
  const float* Wtran = (const float*)d_in[2];
  const float* btran = (const float*)d_in[3];
  const float* Wq    = (const float*)d_in[4];
  const float* bq    = (const float*)d_in[5];
  const float* Wk    = (const float*)d_in[6];
  const float* bk    = (const float*)d_in[7];
  const float* Wv    = (const float*)d_in[8];
  const float* bv    = (const float*)d_in[9];
  const float* Wo    = (const float*)d_in[10];
  const float* bo    = (const float*)d_in[11];
  const float* Wihf  = (const float*)d_in[12];
  const float* Whhf  = (const float*)d_in[13];
  const float* bihf  = (const float*)d_in[14];
  const float* bhhf  = (const float*)d_in[15];
  const float* Wihb  = (const float*)d_in[16];
  const float* Whhb  = (const float*)d_in[17];
  const float* bihb  = (const float*)d_in[18];
  const float* bhhb  = (const float*)d_in[19];
  float* out = (float*)d_out;

  const size_t MT = (size_t)B_ * T_;               // 8192
  float* h   = (float*)d_ws;
  float* q   = h   + MT*D_;                        // also attention output (in-place)
  float* kb_ = q   + MT*D_;
  float* vb  = kb_ + MT*D_;
  u16* WtranT = (u16*)(vb + MT*D_);                // 512*1536
  u16* WqT    = WtranT + (size_t)512*1536;         // 2 x 1M each below
  u16* WkT    = WqT + (size_t)2*1024*1024;
  u16* WvT    = WkT + (size_t)2*1024*1024;
  u16* WoT    = WvT + (size_t)2*1024*1024;
  u16* WihFb  = WoT + (size_t)2*1024*1024;         // 768*1024 (native N x K)
  u16* WihBb  = WihFb + (size_t)768*1024;
  __half* WhhFh = (__half*)(WihBb + (size_t)768*1024);
  __half* WhhBh = WhhFh + (size_t)768*256;
  int* lens = (int*)(WhhBh + (size_t)768*256);
  float* gxf = q;                                  // reuse after attention phase
  float* gxb = kb_;

  // --- prep: copy h, convert/transpose weights, lengths ---
  k_copy_h<<<8192, 256, 0, stream>>>(x, h);
  k_transpose_bf16<<<dim3(512/64, 1536/64), 256, 0, stream>>>(Wtran, WtranT, 1536, 512);
  for (int l = 0; l < 2; ++l){
    size_t wo = (size_t)l * D_ * D_;
    k_transpose_bf16<<<dim3(16,16), 256, 0, stream>>>(Wq + wo, WqT + wo, D_, D_);
    k_transpose_bf16<<<dim3(16,16), 256, 0, stream>>>(Wk + wo, WkT + wo, D_, D_);
    k_transpose_bf16<<<dim3(16,16), 256, 0, stream>>>(Wv + wo, WvT + wo, D_, D_);
    k_transpose_bf16<<<dim3(16,16), 256, 0, stream>>>(Wo + wo, WoT + wo, D_, D_);
  }
  {
    int n = 768*1024;
    k_f32_to_bf16<<<(n+255)/256, 256, 0, stream>>>(Wihf, WihFb, n);
    k_f32_to_bf16<<<(n+255)/256, 256, 0, stream>>>(Wihb, WihBb, n);
    int m = 768*256;
    k_f32_to_f16<<<(m+255)/256, 256, 0, stream>>>(Whhf, WhhFh, m);
    k_f32_to_f16<<<(m+255)/256, 256, 0, stream>>>(Whhb, WhhBh, m);
  }
  k_lengths<<<32, 256, 0, stream>>>(mask, lens);

  // --- 2 transformer layers: QKV proj, banded attention, O proj + residual ---
  for (int l = 0; l < 2; ++l){
    size_t wo = (size_t)l * D_ * D_;
    k_gemm<false><<<dim3(8,64), 256, 0, stream>>>(h, D_, WqT + wo, bq + l*D_, nullptr, q,   D_, D_);
    k_gemm<false><<<dim3(8,64), 256, 0, stream>>>(h, D_, WkT + wo, bk + l*D_, nullptr, kb_, D_, D_);
    k_gemm<false><<<dim3(8,64), 256, 0, stream>>>(h, D_, WvT + wo, bv + l*D_, nullptr, vb,  D_, D_);
    k_attn<<<B_*H_*T_, 64, 0, stream>>>(q, kb_, vb, q);
    k_gemm<true><<<dim3(8,64), 256, 0, stream>>>(q, D_, WoT + wo, bo + l*D_, h, h, D_, D_);
  }

  // --- GRU: input GEMMs then fused bidirectional scan (writes d_out halves) ---
  k_gemm<false><<<dim3(6,64), 256, 0, stream>>>(h, D_, WihFb, bihf, nullptr, gxf, D_, 768);
  k_gemm<false><<<dim3(6,64), 256, 0, stream>>>(h, D_, WihBb, bihb, nullptr, gxb, D_, 768);
  k_gru<<<64, 512, 0, stream>>>(WhhFh, WhhBh, bhhf, bhhb, gxf, gxb, lens, out);

  // --- final: d_out += x[:, :, 1024:] @ W_tran + b_tran ---
  k_gemm<true><<<dim3(4,64), 256, 0, stream>>>(x + 1024, 2560, WtranT, btran, out, out, 1536, 512);
}

// Round 3
// 1099.315 us; speedup vs baseline: 1.2898x; 1.2898x over previous
//
#include <hip/hip_runtime.h>
#include <hip/hip_fp16.h>

#define B_   32
#define T_   256
#define D_   1024
#define H_   8
#define HID_ 256

typedef unsigned short u16;
typedef __attribute__((ext_vector_type(8))) short  s16x8;
typedef __attribute__((ext_vector_type(8))) __bf16 bf16x8;
typedef __attribute__((ext_vector_type(4))) float  f32x4;
typedef __attribute__((ext_vector_type(2))) _Float16 h2v;
typedef __attribute__((ext_vector_type(8))) _Float16 h8;

__device__ __forceinline__ u16 f2bf(float f){
  union { float f; unsigned u; } v; v.f = f;
  unsigned r = v.u + 0x7FFFu + ((v.u >> 16) & 1u);   // RNE
  return (u16)(r >> 16);
}
__device__ __forceinline__ float bf2f(u16 u){
  union { unsigned u; float f; } v; v.u = ((unsigned)u) << 16; return v.f;
}

__device__ __forceinline__ f32x4 mfma_bf16(s16x8 a, s16x8 b, f32x4 c){
  bf16x8 av, bv;
  __builtin_memcpy(&av, &a, 16);
  __builtin_memcpy(&bv, &b, 16);
  return __builtin_amdgcn_mfma_f32_16x16x32_bf16(av, bv, c, 0, 0, 0);
}

__device__ __forceinline__ void gld16(const void* g, void* l){
  __builtin_amdgcn_global_load_lds((const __attribute__((address_space(1))) void*)g,
                                   (__attribute__((address_space(3))) void*)l, 16, 0, 0);
}

#if defined(__has_builtin)
#if __has_builtin(__builtin_amdgcn_fdot2)
#define HAVE_FDOT2 1
#endif
#endif

__device__ __forceinline__ float fdot2f(h2v a, h2v b, float c){
#ifdef HAVE_FDOT2
  return __builtin_amdgcn_fdot2(a, b, c, false);
#else
  return c + (float)a[0]*(float)b[0] + (float)a[1]*(float)b[1];
#endif
}

// ---------- x -> h (bf16 first 1024 cols) + xfb (bf16 last 1536 cols) ----------
__global__ void k_conv_x(const float* __restrict__ x, u16* __restrict__ h,
                         u16* __restrict__ xfb){
  int m = blockIdx.x;
  int i = threadIdx.x * 8;                 // 320 threads * 8 = 2560
  const float4* p = (const float4*)(x + (size_t)m*2560 + i);
  float4 a = p[0], b = p[1];
  union { u16 u[8]; uint4 v; } o;
  o.u[0]=f2bf(a.x); o.u[1]=f2bf(a.y); o.u[2]=f2bf(a.z); o.u[3]=f2bf(a.w);
  o.u[4]=f2bf(b.x); o.u[5]=f2bf(b.y); o.u[6]=f2bf(b.z); o.u[7]=f2bf(b.w);
  u16* dst = (i < 1024) ? (h + (size_t)m*1024 + i) : (xfb + (size_t)m*1536 + (i-1024));
  *(uint4*)dst = o.v;
}

// ---------- transpose K x N fp32 -> N x K bf16 ----------
__global__ void k_transpose_bf16(const float* __restrict__ in, u16* __restrict__ out,
                                 int K, int N){
  __shared__ u16 tile[64][65];
  int kb = blockIdx.y * 64, nb = blockIdx.x * 64;
  int tid = threadIdx.x;
  {
    int k  = tid >> 2;
    int n0 = (tid & 3) * 16;
    const float* ip = in + (size_t)(kb + k) * N + nb + n0;
    #pragma unroll
    for (int i = 0; i < 4; ++i){
      float4 v = *(const float4*)(ip + i*4);
      tile[k][n0 + i*4 + 0] = f2bf(v.x);
      tile[k][n0 + i*4 + 1] = f2bf(v.y);
      tile[k][n0 + i*4 + 2] = f2bf(v.z);
      tile[k][n0 + i*4 + 3] = f2bf(v.w);
    }
  }
  __syncthreads();
  {
    int n  = tid >> 2;
    int k0 = (tid & 3) * 16;
    union { u16 u[16]; uint4 v[2]; } p;
    #pragma unroll
    for (int i = 0; i < 16; ++i) p.u[i] = tile[k0 + i][n];
    uint4* op = (uint4*)(out + (size_t)(nb + n) * K + kb + k0);
    op[0] = p.v[0]; op[1] = p.v[1];
  }
}

__global__ void k_f32_to_bf16(const float* __restrict__ in, u16* __restrict__ out, int n){
  int i = blockIdx.x * blockDim.x + threadIdx.x;
  if (i < n) out[i] = f2bf(in[i]);
}
__global__ void k_f32_to_f16(const float* __restrict__ in, _Float16* __restrict__ out, int n){
  int i = blockIdx.x * blockDim.x + threadIdx.x;
  if (i < n) out[i] = (_Float16)in[i];
}
__global__ void k_copy_f32(const float* __restrict__ in, float* __restrict__ out, int n){
  int i = blockIdx.x * blockDim.x + threadIdx.x;
  if (i < n) out[i] = in[i];
}

__global__ void k_lengths(const int* __restrict__ mask, int* __restrict__ len){
  int b = blockIdx.x;
  int v = mask[b * T_ + threadIdx.x];
  #pragma unroll
  for (int off = 1; off < 64; off <<= 1) v += __shfl_xor(v, off);
  __shared__ int s[4];
  if ((threadIdx.x & 63) == 0) s[threadIdx.x >> 6] = v;
  __syncthreads();
  if (threadIdx.x == 0) len[b] = s[0] + s[1] + s[2] + s[3];
}

// ---------- GEMM: out[M,N] = A[M,K](bf16,lda) @ Wb[N,K](bf16)^T + bias (+res) ----
// 128x128 tile, BK=32, 256 threads (4 waves 2x2, each 64x64), global_load_lds x16.
// MODE: 0 f32 out; 1 bf16 out; 2 bf16 out + bf16 res; 3 f32 out + f32 res.
template<int MODE>
__global__ __launch_bounds__(256, 2)
void k_gemm(const u16* __restrict__ A, int lda,
            const u16* __restrict__ Wb,
            const float* __restrict__ bias,
            const void* __restrict__ resv,
            void* __restrict__ outv,
            int K, int N)
{
  __shared__ __align__(16) u16 As[4*128*8];  // [kh][row][8]
  __shared__ __align__(16) u16 Bs[4*128*8];  // [kh][n][8]
  int tid = threadIdx.x;
  int n0 = blockIdx.x * 128, m0 = blockIdx.y * 128;
  int lane = tid & 63, w = tid >> 6;
  int wm = w >> 1, wn = w & 1;
  int lrow = lane & 15, lq = lane >> 4;
  f32x4 acc[4][4] = {};

  int row = tid & 127;
  int kh0 = tid >> 7;                               // 0..1 (second chunk is +2)
  const u16* aG0 = A  + (size_t)(m0 + row) * lda + kh0 * 8;
  const u16* bG0 = Wb + (size_t)(n0 + row) * K   + kh0 * 8;
  u16* aL0 = &As[((kh0    )*128 + row) * 8];
  u16* aL1 = &As[((kh0 + 2)*128 + row) * 8];
  u16* bL0 = &Bs[((kh0    )*128 + row) * 8];
  u16* bL1 = &Bs[((kh0 + 2)*128 + row) * 8];

  for (int k0 = 0; k0 < K; k0 += 32){
    gld16(aG0 + k0,      aL0);
    gld16(aG0 + k0 + 16, aL1);
    gld16(bG0 + k0,      bL0);
    gld16(bG0 + k0 + 16, bL1);
    __syncthreads();

    s16x8 af[4], bfr[4];
    #pragma unroll
    for (int mt = 0; mt < 4; ++mt)
      af[mt] = *(const s16x8*)&As[(lq*128 + wm*64 + mt*16 + lrow) * 8];
    #pragma unroll
    for (int nt = 0; nt < 4; ++nt)
      bfr[nt] = *(const s16x8*)&Bs[(lq*128 + wn*64 + nt*16 + lrow) * 8];
    #pragma unroll
    for (int mt = 0; mt < 4; ++mt)
      #pragma unroll
      for (int nt = 0; nt < 4; ++nt)
        acc[mt][nt] = mfma_bf16(af[mt], bfr[nt], acc[mt][nt]);
    __syncthreads();
  }

  #pragma unroll
  for (int mt = 0; mt < 4; ++mt){
    int rowb = m0 + wm*64 + mt*16 + lq*4;
    #pragma unroll
    for (int nt = 0; nt < 4; ++nt){
      int col = n0 + wn*64 + nt*16 + lrow;
      float bcol = bias[col];
      f32x4 a = acc[mt][nt];
      #pragma unroll
      for (int r = 0; r < 4; ++r){
        size_t idx = (size_t)(rowb + r) * N + col;
        float v = a[r] + bcol;
        if (MODE == 2) v += bf2f(((const u16*)resv)[idx]);
        if (MODE == 3) v += ((const float*)resv)[idx];
        if (MODE == 0 || MODE == 3) ((float*)outv)[idx] = v;
        else                        ((u16*)outv)[idx]   = f2bf(v);
      }
    }
  }
}

// ---------- banded attention (window +-3), 4 waves/block, one wave per (b,h,t) ----
__global__ void k_attn(const u16* __restrict__ qkv, u16* __restrict__ ao){
  int lane = threadIdx.x & 63, wv = threadIdx.x >> 6;
  int bid = blockIdx.x;
  int t  = (bid & 63) * 4 + wv;
  int hh = (bid >> 6) & 7;
  int b  = bid >> 9;
  size_t qb = ((size_t)b*T_ + t)*3072 + hh*128 + lane*2;
  float2 q2;
  { ushort2 u = *(const ushort2*)(qkv + qb); q2.x = bf2f(u.x); q2.y = bf2f(u.y); }
  int jlo = t - 3; if (jlo < 0) jlo = 0;
  int jhi = t + 3; if (jhi > T_ - 1) jhi = T_ - 1;
  const float scale = 0.08838834764831845f;   // 1/sqrt(128)
  float m = -1e30f, sum = 0.f;
  float ox = 0.f, oy = 0.f;
  for (int j = jlo; j <= jhi; ++j){
    size_t kb = ((size_t)b*T_ + j)*3072 + 1024 + hh*128 + lane*2;
    float2 k2, v2;
    { ushort2 u = *(const ushort2*)(qkv + kb);        k2.x = bf2f(u.x); k2.y = bf2f(u.y); }
    { ushort2 u = *(const ushort2*)(qkv + kb + 1024); v2.x = bf2f(u.x); v2.y = bf2f(u.y); }
    float s = q2.x*k2.x + q2.y*k2.y;
    s += __shfl_xor(s, 1);  s += __shfl_xor(s, 2);  s += __shfl_xor(s, 4);
    s += __shfl_xor(s, 8);  s += __shfl_xor(s, 16); s += __shfl_xor(s, 32);
    float f  = s * scale;
    float nm = fmaxf(m, f);
    float c  = __expf(m - nm);
    float p  = __expf(f - nm);
    sum = sum*c + p;
    ox = ox*c + p*v2.x;
    oy = oy*c + p*v2.y;
    m = nm;
  }
  float inv = 1.f / sum;
  size_t ob = ((size_t)b*T_ + t)*1024 + hh*128 + lane*2;
  ushort2 r; r.x = f2bf(ox*inv); r.y = f2bf(oy*inv);
  *(ushort2*)(ao + ob) = r;
}

// ---------- GRU scan: 1024 thr/block, one block per (dir,b), W_hh in regs (f16) ----
// thread = (j, kc): j = tid>>2 output row, kc = tid&3 k-quarter (interleaved 16B chunks)
__global__ __launch_bounds__(1024, 4)
void k_gru(const _Float16* __restrict__ WhhF, const _Float16* __restrict__ WhhB,
           const float* __restrict__ bhhF, const float* __restrict__ bhhB,
           const float* __restrict__ gx,   // [B*T][1536]: dir*768 + {r,z,n}*256
           const int* __restrict__ lengths, float* __restrict__ out)
{
  int dir = blockIdx.x >> 5, b = blockIdx.x & 31;
  const _Float16* Whh = dir ? WhhB : WhhF;
  const float*    bhh = dir ? bhhB : bhhF;
  int tid = threadIdx.x;
  int j = tid >> 2, kc = tid & 3;

  // weights: gate g row (g*256+j); this thread's k chunks ci = c*4+kc (8 halves each)
  h8 wgt[3][8];
  #pragma unroll
  for (int g = 0; g < 3; ++g)
    #pragma unroll
    for (int c = 0; c < 8; ++c)
      wgt[g][c] = *(const h8*)(Whh + (size_t)(g*256 + j)*256 + (c*4 + kc)*8);
  float bb0 = bhh[j], bb1 = bhh[256 + j], bb2 = bhh[512 + j];

  __shared__ __align__(16) _Float16 hc[2][256];
  if (tid < 256) hc[0][tid] = (_Float16)0.f;
  int len = lengths[b];
  if (tid < 256){
    for (int t = len; t < T_; ++t)
      out[((size_t)b*T_ + t)*512 + dir*256 + tid] = 0.f;
  }
  float hprev = 0.f;
  float gR = 0.f, gZ = 0.f, gN = 0.f;
  if (kc == 0 && len > 0){
    int tt0 = dir ? (len - 1) : 0;
    size_t gb = ((size_t)b*T_ + tt0)*1536 + dir*768 + j;
    gR = gx[gb]; gZ = gx[gb + 256]; gN = gx[gb + 512];
  }
  __syncthreads();

  for (int s = 0; s < len; ++s){
    // prefetch next step's gx off the critical path
    float nR = 0.f, nZ = 0.f, nN = 0.f;
    if (kc == 0 && s + 1 < len){
      int tn = dir ? (len - 2 - s) : (s + 1);
      size_t gb = ((size_t)b*T_ + tn)*1536 + dir*768 + j;
      nR = gx[gb]; nZ = gx[gb + 256]; nN = gx[gb + 512];
    }
    const _Float16* hbuf = hc[s & 1];
    float aR = 0.f, aZ = 0.f, aN = 0.f;
    #pragma unroll
    for (int c = 0; c < 8; ++c){
      h8 hv = *(const h8*)(hbuf + (c*4 + kc)*8);
      h8 w0v = wgt[0][c], w1v = wgt[1][c], w2v = wgt[2][c];
#define GRU_DOT(i) {                                                          \
      h2v hp = __builtin_shufflevector(hv, hv, 2*(i), 2*(i)+1);               \
      aR = fdot2f(__builtin_shufflevector(w0v, w0v, 2*(i), 2*(i)+1), hp, aR); \
      aZ = fdot2f(__builtin_shufflevector(w1v, w1v, 2*(i), 2*(i)+1), hp, aZ); \
      aN = fdot2f(__builtin_shufflevector(w2v, w2v, 2*(i), 2*(i)+1), hp, aN); }
      GRU_DOT(0) GRU_DOT(1) GRU_DOT(2) GRU_DOT(3)
#undef GRU_DOT
    }
    aR += __shfl_xor(aR, 1); aR += __shfl_xor(aR, 2);
    aZ += __shfl_xor(aZ, 1); aZ += __shfl_xor(aZ, 2);
    aN += __shfl_xor(aN, 1); aN += __shfl_xor(aN, 2);
    if (kc == 0){
      int tt = dir ? (len - 1 - s) : s;
      float r = 1.f / (1.f + __expf(-(gR + aR + bb0)));
      float z = 1.f / (1.f + __expf(-(gZ + aZ + bb1)));
      float e = __expf(2.f*(gN + r*(aN + bb2)));
      float n = 1.f - 2.f/(e + 1.f);                 // tanh
      float hnew = (1.f - z)*n + z*hprev;
      hprev = hnew;
      out[((size_t)b*T_ + tt)*512 + dir*256 + j] = hnew;
      hc[(s + 1) & 1][j] = (_Float16)hnew;
    }
    gR = nR; gZ = nZ; gN = nN;
    __syncthreads();
  }
}

extern "C" void kernel_launch(void* const* d_in, const int* in_sizes, int n_in,
                              void* d_out, int out_size, void* d_ws, size_t ws_size,
                              hipStream_t stream)
{
  const float* x     = (const float*)d_in[0];
  const int*   mask  = (const int*)  d_in[1];
  const float* Wtran = (const float*)d_in[2];
  const float* btran = (const float*)d_in[3];
  const float* Wq    = (const float*)d_in[4];
  const float* bq    = (const float*)d_in[5];
  const float* Wk    = (const float*)d_in[6];
  const float* bk    = (const float*)d_in[7];
  const float* Wv    = (const float*)d_in[8];
  const float* bv    = (const float*)d_in[9];
  const float* Wo    = (const float*)d_in[10];
  const float* bo    = (const float*)d_in[11];
  const float* Wihf  = (const float*)d_in[12];
  const float* Whhf  = (const float*)d_in[13];
  const float* bihf  = (const float*)d_in[14];
  const float* bhhf  = (const float*)d_in[15];
  const float* Wihb  = (const float*)d_in[16];
  const float* Whhb  = (const float*)d_in[17];
  const float* bihb  = (const float*)d_in[18];
  const float* bhhb  = (const float*)d_in[19];
  float* out = (float*)d_out;

  char* ws = (char*)d_ws;
  const size_t MT = (size_t)B_ * T_;                       // 8192
  u16* h      = (u16*)(ws);                                // 16.8 MB
  u16* xfb    = (u16*)(ws + 16777216);                     // 25.2 MB
  u16* ao     = (u16*)(ws + 41943040);                     // 16.8 MB
  u16* qkv    = (u16*)(ws + 58720256);                     // 50.3 MB (gx overlays)
  float* gx   = (float*)qkv;                               // fp32 [MT][1536], same size
  u16* WtranT = (u16*)(ws + 109051904);                    // 1.6 MB
  u16* WqkvT  = (u16*)(ws + 110624768);                    // 12.6 MB (2 layers x [3072][1024])
  u16* WoT    = (u16*)(ws + 123207680);                    // 4.2 MB
  u16* WihCat = (u16*)(ws + 127401984);                    // 3.1 MB  [1536][1024]
  _Float16* WhhFh = (_Float16*)(ws + 130547712);           // 0.4 MB
  _Float16* WhhBh = WhhFh + (size_t)768*256;
  float* qkvB  = (float*)(ws + 131334144);                 // 2 x 3072
  float* bihCat= (float*)(ws + 131358720);                 // 1536
  int* lens    = (int*)(ws + 131364864);

  // --- prep ---
  k_conv_x<<<8192, 320, 0, stream>>>(x, h, xfb);
  k_transpose_bf16<<<dim3(8, 24), 256, 0, stream>>>(Wtran, WtranT, 1536, 512);
  for (int l = 0; l < 2; ++l){
    size_t wo = (size_t)l * D_ * D_;
    size_t qo = (size_t)l * 3 * D_ * D_;
    k_transpose_bf16<<<dim3(16,16), 256, 0, stream>>>(Wq + wo, WqkvT + qo,               D_, D_);
    k_transpose_bf16<<<dim3(16,16), 256, 0, stream>>>(Wk + wo, WqkvT + qo + (size_t)D_*D_,   D_, D_);
    k_transpose_bf16<<<dim3(16,16), 256, 0, stream>>>(Wv + wo, WqkvT + qo + (size_t)2*D_*D_, D_, D_);
    k_transpose_bf16<<<dim3(16,16), 256, 0, stream>>>(Wo + wo, WoT + wo, D_, D_);
    k_copy_f32<<<4, 256, 0, stream>>>(bq + l*D_, qkvB + l*3072,        D_);
    k_copy_f32<<<4, 256, 0, stream>>>(bk + l*D_, qkvB + l*3072 + 1024, D_);
    k_copy_f32<<<4, 256, 0, stream>>>(bv + l*D_, qkvB + l*3072 + 2048, D_);
  }
  {
    int n = 768*1024;
    k_f32_to_bf16<<<(n+255)/256, 256, 0, stream>>>(Wihf, WihCat, n);
    k_f32_to_bf16<<<(n+255)/256, 256, 0, stream>>>(Wihb, WihCat + (size_t)768*1024, n);
    int m = 768*256;
    k_f32_to_f16<<<(m+255)/256, 256, 0, stream>>>(Whhf, WhhFh, m);
    k_f32_to_f16<<<(m+255)/256, 256, 0, stream>>>(Whhb, WhhBh, m);
    k_copy_f32<<<3, 256, 0, stream>>>(bihf, bihCat,       768);
    k_copy_f32<<<3, 256, 0, stream>>>(bihb, bihCat + 768, 768);
  }
  k_lengths<<<32, 256, 0, stream>>>(mask, lens);

  // --- 2 transformer layers ---
  for (int l = 0; l < 2; ++l){
    size_t qo = (size_t)l * 3 * D_ * D_;
    size_t wo = (size_t)l * D_ * D_;
    // fused QKV: [8192,1024] @ [3072,1024]^T -> bf16 [8192,3072]
    k_gemm<1><<<dim3(24,64), 256, 0, stream>>>(h, D_, WqkvT + qo, qkvB + l*3072,
                                               nullptr, qkv, D_, 3072);
    k_attn<<<16384, 256, 0, stream>>>(qkv, ao);
    // O-proj + residual (bf16): h = h + ao @ Wo^T + bo
    k_gemm<2><<<dim3(8,64), 256, 0, stream>>>(ao, D_, WoT + wo, bo + l*D_,
                                              h, h, D_, D_);
  }

  // --- GRU input GEMM (both dirs fused): gx[MT][1536] fp32 ---
  k_gemm<0><<<dim3(12,64), 256, 0, stream>>>(h, D_, WihCat, bihCat,
                                             nullptr, gx, D_, 1536);
  k_gru<<<64, 1024, 0, stream>>>(WhhFh, WhhBh, bhhf, bhhb, gx, lens, out);

  // --- final: d_out += x[:, :, 1024:] @ W_tran + b_tran ---
  k_gemm<3><<<dim3(4,64), 256, 0, stream>>>(xfb, 1536, WtranT, btran,
                                            out, out, 1536, 512);
}

// Round 4
// 1079.787 us; speedup vs baseline: 1.3131x; 1.0181x over previous
//
#include <hip/hip_runtime.h>
#include <hip/hip_fp16.h>

#define B_   32
#define T_   256
#define D_   1024
#define H_   8
#define HID_ 256

typedef unsigned short u16;
typedef __attribute__((ext_vector_type(8))) short  s16x8;
typedef __attribute__((ext_vector_type(8))) __bf16 bf16x8;
typedef __attribute__((ext_vector_type(4))) float  f32x4;
typedef __attribute__((ext_vector_type(2))) _Float16 h2v;
typedef __attribute__((ext_vector_type(8))) _Float16 h8;

__device__ __forceinline__ u16 f2bf(float f){
  union { float f; unsigned u; } v; v.f = f;
  unsigned r = v.u + 0x7FFFu + ((v.u >> 16) & 1u);   // RNE
  return (u16)(r >> 16);
}
__device__ __forceinline__ float bf2f(u16 u){
  union { unsigned u; float f; } v; v.u = ((unsigned)u) << 16; return v.f;
}

__device__ __forceinline__ f32x4 mfma_bf16(s16x8 a, s16x8 b, f32x4 c){
  bf16x8 av, bv;
  __builtin_memcpy(&av, &a, 16);
  __builtin_memcpy(&bv, &b, 16);
  return __builtin_amdgcn_mfma_f32_16x16x32_bf16(av, bv, c, 0, 0, 0);
}

__device__ __forceinline__ void gld16(const void* g, void* l){
  __builtin_amdgcn_global_load_lds((const __attribute__((address_space(1))) void*)g,
                                   (__attribute__((address_space(3))) void*)l, 16, 0, 0);
}

#if defined(__has_builtin)
#if __has_builtin(__builtin_amdgcn_fdot2)
#define HAVE_FDOT2 1
#endif
#endif

__device__ __forceinline__ float fdot2f(h2v a, h2v b, float c){
#ifdef HAVE_FDOT2
  return __builtin_amdgcn_fdot2(a, b, c, false);
#else
  return c + (float)a[0]*(float)b[0] + (float)a[1]*(float)b[1];
#endif
}

// ---------- x -> h (bf16 first 1024 cols) + xfb (bf16 last 1536 cols) ----------
__global__ void k_conv_x(const float* __restrict__ x, u16* __restrict__ h,
                         u16* __restrict__ xfb){
  int m = blockIdx.x;
  int i = threadIdx.x * 8;                 // 320 threads * 8 = 2560
  const float4* p = (const float4*)(x + (size_t)m*2560 + i);
  float4 a = p[0], b = p[1];
  union { u16 u[8]; uint4 v; } o;
  o.u[0]=f2bf(a.x); o.u[1]=f2bf(a.y); o.u[2]=f2bf(a.z); o.u[3]=f2bf(a.w);
  o.u[4]=f2bf(b.x); o.u[5]=f2bf(b.y); o.u[6]=f2bf(b.z); o.u[7]=f2bf(b.w);
  u16* dst = (i < 1024) ? (h + (size_t)m*1024 + i) : (xfb + (size_t)m*1536 + (i-1024));
  *(uint4*)dst = o.v;
}

// ---------- transpose K x N fp32 -> N x K bf16 ----------
__global__ void k_transpose_bf16(const float* __restrict__ in, u16* __restrict__ out,
                                 int K, int N){
  __shared__ u16 tile[64][65];
  int kb = blockIdx.y * 64, nb = blockIdx.x * 64;
  int tid = threadIdx.x;
  {
    int k  = tid >> 2;
    int n0 = (tid & 3) * 16;
    const float* ip = in + (size_t)(kb + k) * N + nb + n0;
    #pragma unroll
    for (int i = 0; i < 4; ++i){
      float4 v = *(const float4*)(ip + i*4);
      tile[k][n0 + i*4 + 0] = f2bf(v.x);
      tile[k][n0 + i*4 + 1] = f2bf(v.y);
      tile[k][n0 + i*4 + 2] = f2bf(v.z);
      tile[k][n0 + i*4 + 3] = f2bf(v.w);
    }
  }
  __syncthreads();
  {
    int n  = tid >> 2;
    int k0 = (tid & 3) * 16;
    union { u16 u[16]; uint4 v[2]; } p;
    #pragma unroll
    for (int i = 0; i < 16; ++i) p.u[i] = tile[k0 + i][n];
    uint4* op = (uint4*)(out + (size_t)(nb + n) * K + kb + k0);
    op[0] = p.v[0]; op[1] = p.v[1];
  }
}

__global__ void k_f32_to_bf16(const float* __restrict__ in, u16* __restrict__ out, int n){
  int i = blockIdx.x * blockDim.x + threadIdx.x;
  if (i < n) out[i] = f2bf(in[i]);
}
__global__ void k_f32_to_f16(const float* __restrict__ in, _Float16* __restrict__ out, int n){
  int i = blockIdx.x * blockDim.x + threadIdx.x;
  if (i < n) out[i] = (_Float16)in[i];
}
__global__ void k_copy_f32(const float* __restrict__ in, float* __restrict__ out, int n){
  int i = blockIdx.x * blockDim.x + threadIdx.x;
  if (i < n) out[i] = in[i];
}

__global__ void k_lengths(const int* __restrict__ mask, int* __restrict__ len){
  int b = blockIdx.x;
  int v = mask[b * T_ + threadIdx.x];
  #pragma unroll
  for (int off = 1; off < 64; off <<= 1) v += __shfl_xor(v, off);
  __shared__ int s[4];
  if ((threadIdx.x & 63) == 0) s[threadIdx.x >> 6] = v;
  __syncthreads();
  if (threadIdx.x == 0) len[b] = s[0] + s[1] + s[2] + s[3];
}

// ---------- GEMM: out[M,N] = A[M,K](bf16,lda) @ Wb[N,K](bf16)^T + bias (+res) ----
// 128x128 tile, BK=64, 256 threads (4 waves 2x2, each 64x64), global_load_lds x16.
// MODE: 0 f32 out; 1 bf16 out; 2 bf16 out + bf16 res; 3 f32 out + f32 res.
template<int MODE>
__global__ __launch_bounds__(256, 2)
void k_gemm(const u16* __restrict__ A, int lda,
            const u16* __restrict__ Wb,
            const float* __restrict__ bias,
            const void* __restrict__ resv,
            void* __restrict__ outv,
            int K, int N)
{
  __shared__ __align__(16) u16 As[8*128*8];  // [kh][row][8]
  __shared__ __align__(16) u16 Bs[8*128*8];  // [kh][n][8]
  int tid = threadIdx.x;
  int n0 = blockIdx.x * 128, m0 = blockIdx.y * 128;
  int lane = tid & 63, w = tid >> 6;
  int wm = w >> 1, wn = w & 1;
  int lrow = lane & 15, lq = lane >> 4;
  f32x4 acc[4][4] = {};

  int row = tid & 127;
  int kh0 = tid >> 7;                               // 0..1; chunks kh0, kh0+2, +4, +6
  const u16* aG = A  + (size_t)(m0 + row) * lda + kh0 * 8;
  const u16* bG = Wb + (size_t)(n0 + row) * K   + kh0 * 8;
  u16* aL[4]; u16* bL[4];
  #pragma unroll
  for (int c = 0; c < 4; ++c){
    aL[c] = &As[((kh0 + 2*c)*128 + row) * 8];
    bL[c] = &Bs[((kh0 + 2*c)*128 + row) * 8];
  }

  for (int k0 = 0; k0 < K; k0 += 64){
    #pragma unroll
    for (int c = 0; c < 4; ++c){
      gld16(aG + k0 + c*16, aL[c]);
      gld16(bG + k0 + c*16, bL[c]);
    }
    __syncthreads();

    s16x8 af[2][4], bfr[2][4];
    #pragma unroll
    for (int ks = 0; ks < 2; ++ks){
      #pragma unroll
      for (int mt = 0; mt < 4; ++mt)
        af[ks][mt] = *(const s16x8*)&As[((ks*4 + lq)*128 + wm*64 + mt*16 + lrow) * 8];
      #pragma unroll
      for (int nt = 0; nt < 4; ++nt)
        bfr[ks][nt] = *(const s16x8*)&Bs[((ks*4 + lq)*128 + wn*64 + nt*16 + lrow) * 8];
    }
    #pragma unroll
    for (int ks = 0; ks < 2; ++ks)
      #pragma unroll
      for (int mt = 0; mt < 4; ++mt)
        #pragma unroll
        for (int nt = 0; nt < 4; ++nt)
          acc[mt][nt] = mfma_bf16(af[ks][mt], bfr[ks][nt], acc[mt][nt]);
    __syncthreads();
  }

  #pragma unroll
  for (int mt = 0; mt < 4; ++mt){
    int rowb = m0 + wm*64 + mt*16 + lq*4;
    #pragma unroll
    for (int nt = 0; nt < 4; ++nt){
      int col = n0 + wn*64 + nt*16 + lrow;
      float bcol = bias[col];
      f32x4 a = acc[mt][nt];
      #pragma unroll
      for (int r = 0; r < 4; ++r){
        size_t idx = (size_t)(rowb + r) * N + col;
        float v = a[r] + bcol;
        if (MODE == 2) v += bf2f(((const u16*)resv)[idx]);
        if (MODE == 3) v += ((const float*)resv)[idx];
        if (MODE == 0 || MODE == 3) ((float*)outv)[idx] = v;
        else                        ((u16*)outv)[idx]   = f2bf(v);
      }
    }
  }
}

// ---------- banded attention (window +-3), 4 waves/block, one wave per (b,h,t) ----
__global__ void k_attn(const u16* __restrict__ qkv, u16* __restrict__ ao){
  int lane = threadIdx.x & 63, wv = threadIdx.x >> 6;
  int bid = blockIdx.x;
  int t  = (bid & 63) * 4 + wv;
  int hh = (bid >> 6) & 7;
  int b  = bid >> 9;
  size_t qb = ((size_t)b*T_ + t)*3072 + hh*128 + lane*2;
  float2 q2;
  { ushort2 u = *(const ushort2*)(qkv + qb); q2.x = bf2f(u.x); q2.y = bf2f(u.y); }
  int jlo = t - 3; if (jlo < 0) jlo = 0;
  int jhi = t + 3; if (jhi > T_ - 1) jhi = T_ - 1;
  const float scale = 0.08838834764831845f;   // 1/sqrt(128)
  float m = -1e30f, sum = 0.f;
  float ox = 0.f, oy = 0.f;
  for (int j = jlo; j <= jhi; ++j){
    size_t kb = ((size_t)b*T_ + j)*3072 + 1024 + hh*128 + lane*2;
    float2 k2, v2;
    { ushort2 u = *(const ushort2*)(qkv + kb);        k2.x = bf2f(u.x); k2.y = bf2f(u.y); }
    { ushort2 u = *(const ushort2*)(qkv + kb + 1024); v2.x = bf2f(u.x); v2.y = bf2f(u.y); }
    float s = q2.x*k2.x + q2.y*k2.y;
    s += __shfl_xor(s, 1);  s += __shfl_xor(s, 2);  s += __shfl_xor(s, 4);
    s += __shfl_xor(s, 8);  s += __shfl_xor(s, 16); s += __shfl_xor(s, 32);
    float f  = s * scale;
    float nm = fmaxf(m, f);
    float c  = __expf(m - nm);
    float p  = __expf(f - nm);
    sum = sum*c + p;
    ox = ox*c + p*v2.x;
    oy = oy*c + p*v2.y;
    m = nm;
  }
  float inv = 1.f / sum;
  size_t ob = ((size_t)b*T_ + t)*1024 + hh*128 + lane*2;
  ushort2 r; r.x = f2bf(ox*inv); r.y = f2bf(oy*inv);
  *(ushort2*)(ao + ob) = r;
}

// ---------- GRU scan: 512 thr/block, one block per (dir,b), W_hh pinned in VGPRs ----
// thread = (j, kc): j = tid>>1 output row, kc = tid&1 k-half (interleaved 16B chunks)
__global__ __launch_bounds__(512, 2)
void k_gru(const _Float16* __restrict__ WhhF, const _Float16* __restrict__ WhhB,
           const float* __restrict__ bhhF, const float* __restrict__ bhhB,
           const float* __restrict__ gx,   // [B*T][1536]: dir*768 + {r,z,n}*256
           const int* __restrict__ lengths, float* __restrict__ out)
{
  int dir = blockIdx.x >> 5, b = blockIdx.x & 31;
  const _Float16* Whh = dir ? WhhB : WhhF;
  const float*    bhh = dir ? bhhB : bhhF;
  int tid = threadIdx.x;
  int j = tid >> 1, kc = tid & 1;

  // weights: gate g row (g*256+j); this thread's k chunks ci = c*2+kc (8 halves each)
  h8 wgt[3][16];
  #pragma unroll
  for (int g = 0; g < 3; ++g)
    #pragma unroll
    for (int c = 0; c < 16; ++c)
      wgt[g][c] = *(const h8*)(Whh + (size_t)(g*256 + j)*256 + (c*2 + kc)*8);
  // Pin in VGPRs: asm-defined values cannot be rematerialized by re-loading,
  // so the allocator must keep all 192 weight VGPRs live across the scan loop.
  #pragma unroll
  for (int g = 0; g < 3; ++g)
    #pragma unroll
    for (int c = 0; c < 16; ++c)
      asm volatile("" : "+v"(wgt[g][c]));
  float bb0 = bhh[j], bb1 = bhh[256 + j], bb2 = bhh[512 + j];

  __shared__ __align__(16) _Float16 hc[2][256];
  if (tid < 256) hc[0][tid] = (_Float16)0.f;
  int len = lengths[b];
  if (tid < 256){
    for (int t = len; t < T_; ++t)
      out[((size_t)b*T_ + t)*512 + dir*256 + tid] = 0.f;
  }
  float hprev = 0.f;
  float gR = 0.f, gZ = 0.f, gN = 0.f;
  if (kc == 0 && len > 0){
    int tt0 = dir ? (len - 1) : 0;
    size_t gb = ((size_t)b*T_ + tt0)*1536 + dir*768 + j;
    gR = gx[gb]; gZ = gx[gb + 256]; gN = gx[gb + 512];
  }
  __syncthreads();

  for (int s = 0; s < len; ++s){
    // prefetch next step's gx off the critical path
    float nR = 0.f, nZ = 0.f, nN = 0.f;
    if (kc == 0 && s + 1 < len){
      int tn = dir ? (len - 2 - s) : (s + 1);
      size_t gb = ((size_t)b*T_ + tn)*1536 + dir*768 + j;
      nR = gx[gb]; nZ = gx[gb + 256]; nN = gx[gb + 512];
    }
    const _Float16* hbuf = hc[s & 1];
    float aR = 0.f, aZ = 0.f, aN = 0.f;
    #pragma unroll
    for (int c = 0; c < 16; ++c){
      h8 hv = *(const h8*)(hbuf + (c*2 + kc)*8);
      h8 w0v = wgt[0][c], w1v = wgt[1][c], w2v = wgt[2][c];
#define GRU_DOT(i) {                                                          \
      h2v hp = __builtin_shufflevector(hv, hv, 2*(i), 2*(i)+1);               \
      aR = fdot2f(__builtin_shufflevector(w0v, w0v, 2*(i), 2*(i)+1), hp, aR); \
      aZ = fdot2f(__builtin_shufflevector(w1v, w1v, 2*(i), 2*(i)+1), hp, aZ); \
      aN = fdot2f(__builtin_shufflevector(w2v, w2v, 2*(i), 2*(i)+1), hp, aN); }
      GRU_DOT(0) GRU_DOT(1) GRU_DOT(2) GRU_DOT(3)
#undef GRU_DOT
    }
    aR += __shfl_xor(aR, 1);
    aZ += __shfl_xor(aZ, 1);
    aN += __shfl_xor(aN, 1);
    if (kc == 0){
      int tt = dir ? (len - 1 - s) : s;
      float r = 1.f / (1.f + __expf(-(gR + aR + bb0)));
      float z = 1.f / (1.f + __expf(-(gZ + aZ + bb1)));
      float e = __expf(2.f*(gN + r*(aN + bb2)));
      float n = 1.f - 2.f/(e + 1.f);                 // tanh
      float hnew = (1.f - z)*n + z*hprev;
      hprev = hnew;
      out[((size_t)b*T_ + tt)*512 + dir*256 + j] = hnew;
      hc[(s + 1) & 1][j] = (_Float16)hnew;
    }
    gR = nR; gZ = nZ; gN = nN;
    __syncthreads();
  }
}

extern "C" void kernel_launch(void* const* d_in, const int* in_sizes, int n_in,
                              void* d_out, int out_size, void* d_ws, size_t ws_size,
                              hipStream_t stream)
{
  const float* x     = (const float*)d_in[0];
  const int*   mask  = (const int*)  d_in[1];
  const float* Wtran = (const float*)d_in[2];
  const float* btran = (const float*)d_in[3];
  const float* Wq    = (const float*)d_in[4];
  const float* bq    = (const float*)d_in[5];
  const float* Wk    = (const float*)d_in[6];
  const float* bk    = (const float*)d_in[7];
  const float* Wv    = (const float*)d_in[8];
  const float* bv    = (const float*)d_in[9];
  const float* Wo    = (const float*)d_in[10];
  const float* bo    = (const float*)d_in[11];
  const float* Wihf  = (const float*)d_in[12];
  const float* Whhf  = (const float*)d_in[13];
  const float* bihf  = (const float*)d_in[14];
  const float* bhhf  = (const float*)d_in[15];
  const float* Wihb  = (const float*)d_in[16];
  const float* Whhb  = (const float*)d_in[17];
  const float* bihb  = (const float*)d_in[18];
  const float* bhhb  = (const float*)d_in[19];
  float* out = (float*)d_out;

  char* ws = (char*)d_ws;
  const size_t MT = (size_t)B_ * T_;                       // 8192
  u16* h      = (u16*)(ws);                                // 16.8 MB
  u16* xfb    = (u16*)(ws + 16777216);                     // 25.2 MB
  u16* ao     = (u16*)(ws + 41943040);                     // 16.8 MB
  u16* qkv    = (u16*)(ws + 58720256);                     // 50.3 MB (gx overlays)
  float* gx   = (float*)qkv;                               // fp32 [MT][1536], same size
  u16* WtranT = (u16*)(ws + 109051904);                    // 1.6 MB
  u16* WqkvT  = (u16*)(ws + 110624768);                    // 12.6 MB (2 layers x [3072][1024])
  u16* WoT    = (u16*)(ws + 123207680);                    // 4.2 MB
  u16* WihCat = (u16*)(ws + 127401984);                    // 3.1 MB  [1536][1024]
  _Float16* WhhFh = (_Float16*)(ws + 130547712);           // 0.4 MB
  _Float16* WhhBh = WhhFh + (size_t)768*256;
  float* qkvB  = (float*)(ws + 131334144);                 // 2 x 3072
  float* bihCat= (float*)(ws + 131358720);                 // 1536
  int* lens    = (int*)(ws + 131364864);

  // --- prep ---
  k_conv_x<<<8192, 320, 0, stream>>>(x, h, xfb);
  k_transpose_bf16<<<dim3(8, 24), 256, 0, stream>>>(Wtran, WtranT, 1536, 512);
  for (int l = 0; l < 2; ++l){
    size_t wo = (size_t)l * D_ * D_;
    size_t qo = (size_t)l * 3 * D_ * D_;
    k_transpose_bf16<<<dim3(16,16), 256, 0, stream>>>(Wq + wo, WqkvT + qo,               D_, D_);
    k_transpose_bf16<<<dim3(16,16), 256, 0, stream>>>(Wk + wo, WqkvT + qo + (size_t)D_*D_,   D_, D_);
    k_transpose_bf16<<<dim3(16,16), 256, 0, stream>>>(Wv + wo, WqkvT + qo + (size_t)2*D_*D_, D_, D_);
    k_transpose_bf16<<<dim3(16,16), 256, 0, stream>>>(Wo + wo, WoT + wo, D_, D_);
    k_copy_f32<<<4, 256, 0, stream>>>(bq + l*D_, qkvB + l*3072,        D_);
    k_copy_f32<<<4, 256, 0, stream>>>(bk + l*D_, qkvB + l*3072 + 1024, D_);
    k_copy_f32<<<4, 256, 0, stream>>>(bv + l*D_, qkvB + l*3072 + 2048, D_);
  }
  {
    int n = 768*1024;
    k_f32_to_bf16<<<(n+255)/256, 256, 0, stream>>>(Wihf, WihCat, n);
    k_f32_to_bf16<<<(n+255)/256, 256, 0, stream>>>(Wihb, WihCat + (size_t)768*1024, n);
    int m = 768*256;
    k_f32_to_f16<<<(m+255)/256, 256, 0, stream>>>(Whhf, WhhFh, m);
    k_f32_to_f16<<<(m+255)/256, 256, 0, stream>>>(Whhb, WhhBh, m);
    k_copy_f32<<<3, 256, 0, stream>>>(bihf, bihCat,       768);
    k_copy_f32<<<3, 256, 0, stream>>>(bihb, bihCat + 768, 768);
  }
  k_lengths<<<32, 256, 0, stream>>>(mask, lens);

  // --- 2 transformer layers ---
  for (int l = 0; l < 2; ++l){
    size_t qo = (size_t)l * 3 * D_ * D_;
    size_t wo = (size_t)l * D_ * D_;
    // fused QKV: [8192,1024] @ [3072,1024]^T -> bf16 [8192,3072]
    k_gemm<1><<<dim3(24,64), 256, 0, stream>>>(h, D_, WqkvT + qo, qkvB + l*3072,
                                               nullptr, qkv, D_, 3072);
    k_attn<<<16384, 256, 0, stream>>>(qkv, ao);
    // O-proj + residual (bf16): h = h + ao @ Wo^T + bo
    k_gemm<2><<<dim3(8,64), 256, 0, stream>>>(ao, D_, WoT + wo, bo + l*D_,
                                              h, h, D_, D_);
  }

  // --- GRU input GEMM (both dirs fused): gx[MT][1536] fp32 ---
  k_gemm<0><<<dim3(12,64), 256, 0, stream>>>(h, D_, WihCat, bihCat,
                                             nullptr, gx, D_, 1536);
  k_gru<<<64, 512, 0, stream>>>(WhhFh, WhhBh, bhhf, bhhb, gx, lens, out);

  // --- final: d_out += x[:, :, 1024:] @ W_tran + b_tran ---
  k_gemm<3><<<dim3(4,64), 256, 0, stream>>>(xfb, 1536, WtranT, btran,
                                            out, out, 1536, 512);
}

// Round 5
// 1040.332 us; speedup vs baseline: 1.3629x; 1.0379x over previous
//
#include <hip/hip_runtime.h>
#include <hip/hip_fp16.h>

#define B_   32
#define T_   256
#define D_   1024
#define H_   8
#define HID_ 256

typedef unsigned short u16;
typedef __attribute__((ext_vector_type(8))) short  s16x8;
typedef __attribute__((ext_vector_type(8))) __bf16 bf16x8;
typedef __attribute__((ext_vector_type(4))) float  f32x4;
typedef __attribute__((ext_vector_type(2))) _Float16 h2v;
typedef __attribute__((ext_vector_type(8))) _Float16 h8;

__device__ __forceinline__ u16 f2bf(float f){
  union { float f; unsigned u; } v; v.f = f;
  unsigned r = v.u + 0x7FFFu + ((v.u >> 16) & 1u);   // RNE
  return (u16)(r >> 16);
}
__device__ __forceinline__ float bf2f(u16 u){
  union { unsigned u; float f; } v; v.u = ((unsigned)u) << 16; return v.f;
}

__device__ __forceinline__ f32x4 mfma_bf16(s16x8 a, s16x8 b, f32x4 c){
  bf16x8 av, bv;
  __builtin_memcpy(&av, &a, 16);
  __builtin_memcpy(&bv, &b, 16);
  return __builtin_amdgcn_mfma_f32_16x16x32_bf16(av, bv, c, 0, 0, 0);
}

__device__ __forceinline__ void gld16(const void* g, void* l){
  __builtin_amdgcn_global_load_lds((const __attribute__((address_space(1))) void*)g,
                                   (__attribute__((address_space(3))) void*)l, 16, 0, 0);
}

#if defined(__has_builtin)
#if __has_builtin(__builtin_amdgcn_fdot2)
#define HAVE_FDOT2 1
#endif
#endif

__device__ __forceinline__ float fdot2f(h2v a, h2v b, float c){
#ifdef HAVE_FDOT2
  return __builtin_amdgcn_fdot2(a, b, c, false);
#else
  return c + (float)a[0]*(float)b[0] + (float)a[1]*(float)b[1];
#endif
}

// ---------- x -> h (bf16 first 1024 cols) + xfb (bf16 last 1536 cols) ----------
__global__ void k_conv_x(const float* __restrict__ x, u16* __restrict__ h,
                         u16* __restrict__ xfb){
  int m = blockIdx.x;
  int i = threadIdx.x * 8;                 // 320 threads * 8 = 2560
  const float4* p = (const float4*)(x + (size_t)m*2560 + i);
  float4 a = p[0], b = p[1];
  union { u16 u[8]; uint4 v; } o;
  o.u[0]=f2bf(a.x); o.u[1]=f2bf(a.y); o.u[2]=f2bf(a.z); o.u[3]=f2bf(a.w);
  o.u[4]=f2bf(b.x); o.u[5]=f2bf(b.y); o.u[6]=f2bf(b.z); o.u[7]=f2bf(b.w);
  u16* dst = (i < 1024) ? (h + (size_t)m*1024 + i) : (xfb + (size_t)m*1536 + (i-1024));
  *(uint4*)dst = o.v;
}

// ---------- transpose K x N fp32 -> N x K bf16 ----------
__global__ void k_transpose_bf16(const float* __restrict__ in, u16* __restrict__ out,
                                 int K, int N){
  __shared__ u16 tile[64][65];
  int kb = blockIdx.y * 64, nb = blockIdx.x * 64;
  int tid = threadIdx.x;
  {
    int k  = tid >> 2;
    int n0 = (tid & 3) * 16;
    const float* ip = in + (size_t)(kb + k) * N + nb + n0;
    #pragma unroll
    for (int i = 0; i < 4; ++i){
      float4 v = *(const float4*)(ip + i*4);
      tile[k][n0 + i*4 + 0] = f2bf(v.x);
      tile[k][n0 + i*4 + 1] = f2bf(v.y);
      tile[k][n0 + i*4 + 2] = f2bf(v.z);
      tile[k][n0 + i*4 + 3] = f2bf(v.w);
    }
  }
  __syncthreads();
  {
    int n  = tid >> 2;
    int k0 = (tid & 3) * 16;
    union { u16 u[16]; uint4 v[2]; } p;
    #pragma unroll
    for (int i = 0; i < 16; ++i) p.u[i] = tile[k0 + i][n];
    uint4* op = (uint4*)(out + (size_t)(nb + n) * K + kb + k0);
    op[0] = p.v[0]; op[1] = p.v[1];
  }
}

__global__ void k_f32_to_bf16(const float* __restrict__ in, u16* __restrict__ out, int n){
  int i = blockIdx.x * blockDim.x + threadIdx.x;
  if (i < n) out[i] = f2bf(in[i]);
}
__global__ void k_f32_to_f16(const float* __restrict__ in, _Float16* __restrict__ out, int n){
  int i = blockIdx.x * blockDim.x + threadIdx.x;
  if (i < n) out[i] = (_Float16)in[i];
}
__global__ void k_copy_f32(const float* __restrict__ in, float* __restrict__ out, int n){
  int i = blockIdx.x * blockDim.x + threadIdx.x;
  if (i < n) out[i] = in[i];
}

__global__ void k_lengths(const int* __restrict__ mask, int* __restrict__ len){
  int b = blockIdx.x;
  int v = mask[b * T_ + threadIdx.x];
  #pragma unroll
  for (int off = 1; off < 64; off <<= 1) v += __shfl_xor(v, off);
  __shared__ int s[4];
  if ((threadIdx.x & 63) == 0) s[threadIdx.x >> 6] = v;
  __syncthreads();
  if (threadIdx.x == 0) len[b] = s[0] + s[1] + s[2] + s[3];
}

// ---------- GEMM: out[M,N] = A[M,K](bf16,lda) @ Wb[N,K](bf16)^T + bias (+res) ----
// 128x128 tile, BK=32, 256 threads (4 waves 2x2, each 64x64), global_load_lds x16.
// MODE: 0 f32 out; 1 bf16 out; 2 bf16 out + bf16 res; 3 f32 out + f32 res.
template<int MODE>
__global__ __launch_bounds__(256, 2)
void k_gemm(const u16* __restrict__ A, int lda,
            const u16* __restrict__ Wb,
            const float* __restrict__ bias,
            const void* __restrict__ resv,
            void* __restrict__ outv,
            int K, int N)
{
  __shared__ __align__(16) u16 As[4*128*8];  // [kh][row][8]
  __shared__ __align__(16) u16 Bs[4*128*8];  // [kh][n][8]
  int tid = threadIdx.x;
  int n0 = blockIdx.x * 128, m0 = blockIdx.y * 128;
  int lane = tid & 63, w = tid >> 6;
  int wm = w >> 1, wn = w & 1;
  int lrow = lane & 15, lq = lane >> 4;
  f32x4 acc[4][4] = {};

  int row = tid & 127;
  int kh0 = tid >> 7;                               // 0..1 (second chunk is +2)
  const u16* aG0 = A  + (size_t)(m0 + row) * lda + kh0 * 8;
  const u16* bG0 = Wb + (size_t)(n0 + row) * K   + kh0 * 8;
  u16* aL0 = &As[((kh0    )*128 + row) * 8];
  u16* aL1 = &As[((kh0 + 2)*128 + row) * 8];
  u16* bL0 = &Bs[((kh0    )*128 + row) * 8];
  u16* bL1 = &Bs[((kh0 + 2)*128 + row) * 8];

  for (int k0 = 0; k0 < K; k0 += 32){
    gld16(aG0 + k0,      aL0);
    gld16(aG0 + k0 + 16, aL1);
    gld16(bG0 + k0,      bL0);
    gld16(bG0 + k0 + 16, bL1);
    __syncthreads();

    s16x8 af[4], bfr[4];
    #pragma unroll
    for (int mt = 0; mt < 4; ++mt)
      af[mt] = *(const s16x8*)&As[(lq*128 + wm*64 + mt*16 + lrow) * 8];
    #pragma unroll
    for (int nt = 0; nt < 4; ++nt)
      bfr[nt] = *(const s16x8*)&Bs[(lq*128 + wn*64 + nt*16 + lrow) * 8];
    #pragma unroll
    for (int mt = 0; mt < 4; ++mt)
      #pragma unroll
      for (int nt = 0; nt < 4; ++nt)
        acc[mt][nt] = mfma_bf16(af[mt], bfr[nt], acc[mt][nt]);
    __syncthreads();
  }

  #pragma unroll
  for (int mt = 0; mt < 4; ++mt){
    int rowb = m0 + wm*64 + mt*16 + lq*4;
    #pragma unroll
    for (int nt = 0; nt < 4; ++nt){
      int col = n0 + wn*64 + nt*16 + lrow;
      float bcol = bias[col];
      f32x4 a = acc[mt][nt];
      #pragma unroll
      for (int r = 0; r < 4; ++r){
        size_t idx = (size_t)(rowb + r) * N + col;
        float v = a[r] + bcol;
        if (MODE == 2) v += bf2f(((const u16*)resv)[idx]);
        if (MODE == 3) v += ((const float*)resv)[idx];
        if (MODE == 0 || MODE == 3) ((float*)outv)[idx] = v;
        else                        ((u16*)outv)[idx]   = f2bf(v);
      }
    }
  }
}

// ---------- banded attention (window +-3), 4 waves/block, one wave per (b,h,t) ----
__global__ void k_attn(const u16* __restrict__ qkv, u16* __restrict__ ao){
  int lane = threadIdx.x & 63, wv = threadIdx.x >> 6;
  int bid = blockIdx.x;
  int t  = (bid & 63) * 4 + wv;
  int hh = (bid >> 6) & 7;
  int b  = bid >> 9;
  size_t qb = ((size_t)b*T_ + t)*3072 + hh*128 + lane*2;
  float2 q2;
  { ushort2 u = *(const ushort2*)(qkv + qb); q2.x = bf2f(u.x); q2.y = bf2f(u.y); }
  int jlo = t - 3; if (jlo < 0) jlo = 0;
  int jhi = t + 3; if (jhi > T_ - 1) jhi = T_ - 1;
  const float scale = 0.08838834764831845f;   // 1/sqrt(128)
  float m = -1e30f, sum = 0.f;
  float ox = 0.f, oy = 0.f;
  for (int j = jlo; j <= jhi; ++j){
    size_t kb = ((size_t)b*T_ + j)*3072 + 1024 + hh*128 + lane*2;
    float2 k2, v2;
    { ushort2 u = *(const ushort2*)(qkv + kb);        k2.x = bf2f(u.x); k2.y = bf2f(u.y); }
    { ushort2 u = *(const ushort2*)(qkv + kb + 1024); v2.x = bf2f(u.x); v2.y = bf2f(u.y); }
    float s = q2.x*k2.x + q2.y*k2.y;
    s += __shfl_xor(s, 1);  s += __shfl_xor(s, 2);  s += __shfl_xor(s, 4);
    s += __shfl_xor(s, 8);  s += __shfl_xor(s, 16); s += __shfl_xor(s, 32);
    float f  = s * scale;
    float nm = fmaxf(m, f);
    float c  = __expf(m - nm);
    float p  = __expf(f - nm);
    sum = sum*c + p;
    ox = ox*c + p*v2.x;
    oy = oy*c + p*v2.y;
    m = nm;
  }
  float inv = 1.f / sum;
  size_t ob = ((size_t)b*T_ + t)*1024 + hh*128 + lane*2;
  ushort2 r; r.x = f2bf(ox*inv); r.y = f2bf(oy*inv);
  *(ushort2*)(ao + ob) = r;
}

// ---------- GRU scan: 512 thr/block, one block per (dir,b), W_hh pinned in VGPRs ----
// thread = (j, kc): j = tid>>1 output row, kc = tid&1 k-half (interleaved 16B chunks)
// waves_per_eu(2,2): pin the occupancy target so the allocator uses the full
// 256-VGPR budget instead of self-capping at 128 (round-4: VGPR=112 + scratch spill).
__global__ __attribute__((amdgpu_flat_work_group_size(512, 512), amdgpu_waves_per_eu(2, 2)))
void k_gru(const _Float16* __restrict__ WhhF, const _Float16* __restrict__ WhhB,
           const float* __restrict__ bhhF, const float* __restrict__ bhhB,
           const float* __restrict__ gx,   // [B*T][1536]: dir*768 + {r,z,n}*256
           const int* __restrict__ lengths, float* __restrict__ out)
{
  int dir = blockIdx.x >> 5, b = blockIdx.x & 31;
  const _Float16* Whh = dir ? WhhB : WhhF;
  const float*    bhh = dir ? bhhB : bhhF;
  int tid = threadIdx.x;
  int j = tid >> 1, kc = tid & 1;

  // weights: gate g row (g*256+j); this thread's k chunks ci = c*2+kc (8 halves each)
  h8 wgt[3][16];
  #pragma unroll
  for (int g = 0; g < 3; ++g)
    #pragma unroll
    for (int c = 0; c < 16; ++c)
      wgt[g][c] = *(const h8*)(Whh + (size_t)(g*256 + j)*256 + (c*2 + kc)*8);
  // Pin in VGPRs: asm-defined values cannot be rematerialized by re-loading.
  #pragma unroll
  for (int g = 0; g < 3; ++g)
    #pragma unroll
    for (int c = 0; c < 16; ++c)
      asm volatile("" : "+v"(wgt[g][c]));
  float bb0 = bhh[j], bb1 = bhh[256 + j], bb2 = bhh[512 + j];

  __shared__ __align__(16) _Float16 hc[2][256];
  if (tid < 256) hc[0][tid] = (_Float16)0.f;
  int len = lengths[b];
  if (tid < 256){
    for (int t = len; t < T_; ++t)
      out[((size_t)b*T_ + t)*512 + dir*256 + tid] = 0.f;
  }
  float hprev = 0.f;
  float gR = 0.f, gZ = 0.f, gN = 0.f;
  if (kc == 0 && len > 0){
    int tt0 = dir ? (len - 1) : 0;
    size_t gb = ((size_t)b*T_ + tt0)*1536 + dir*768 + j;
    gR = gx[gb]; gZ = gx[gb + 256]; gN = gx[gb + 512];
  }
  __syncthreads();

  for (int s = 0; s < len; ++s){
    // prefetch next step's gx off the critical path
    float nR = 0.f, nZ = 0.f, nN = 0.f;
    if (kc == 0 && s + 1 < len){
      int tn = dir ? (len - 2 - s) : (s + 1);
      size_t gb = ((size_t)b*T_ + tn)*1536 + dir*768 + j;
      nR = gx[gb]; nZ = gx[gb + 256]; nN = gx[gb + 512];
    }
    const _Float16* hbuf = hc[s & 1];
    float aR = 0.f, aZ = 0.f, aN = 0.f;
    #pragma unroll
    for (int c = 0; c < 16; ++c){
      h8 hv = *(const h8*)(hbuf + (c*2 + kc)*8);
      h8 w0v = wgt[0][c], w1v = wgt[1][c], w2v = wgt[2][c];
#define GRU_DOT(i) {                                                          \
      h2v hp = __builtin_shufflevector(hv, hv, 2*(i), 2*(i)+1);               \
      aR = fdot2f(__builtin_shufflevector(w0v, w0v, 2*(i), 2*(i)+1), hp, aR); \
      aZ = fdot2f(__builtin_shufflevector(w1v, w1v, 2*(i), 2*(i)+1), hp, aZ); \
      aN = fdot2f(__builtin_shufflevector(w2v, w2v, 2*(i), 2*(i)+1), hp, aN); }
      GRU_DOT(0) GRU_DOT(1) GRU_DOT(2) GRU_DOT(3)
#undef GRU_DOT
    }
    aR += __shfl_xor(aR, 1);
    aZ += __shfl_xor(aZ, 1);
    aN += __shfl_xor(aN, 1);
    if (kc == 0){
      int tt = dir ? (len - 1 - s) : s;
      float r = 1.f / (1.f + __expf(-(gR + aR + bb0)));
      float z = 1.f / (1.f + __expf(-(gZ + aZ + bb1)));
      float e = __expf(2.f*(gN + r*(aN + bb2)));
      float n = 1.f - 2.f/(e + 1.f);                 // tanh
      float hnew = (1.f - z)*n + z*hprev;
      hprev = hnew;
      out[((size_t)b*T_ + tt)*512 + dir*256 + j] = hnew;
      hc[(s + 1) & 1][j] = (_Float16)hnew;
    }
    gR = nR; gZ = nZ; gN = nN;
    __syncthreads();
  }
}

extern "C" void kernel_launch(void* const* d_in, const int* in_sizes, int n_in,
                              void* d_out, int out_size, void* d_ws, size_t ws_size,
                              hipStream_t stream)
{
  const float* x     = (const float*)d_in[0];
  const int*   mask  = (const int*)  d_in[1];
  const float* Wtran = (const float*)d_in[2];
  const float* btran = (const float*)d_in[3];
  const float* Wq    = (const float*)d_in[4];
  const float* bq    = (const float*)d_in[5];
  const float* Wk    = (const float*)d_in[6];
  const float* bk    = (const float*)d_in[7];
  const float* Wv    = (const float*)d_in[8];
  const float* bv    = (const float*)d_in[9];
  const float* Wo    = (const float*)d_in[10];
  const float* bo    = (const float*)d_in[11];
  const float* Wihf  = (const float*)d_in[12];
  const float* Whhf  = (const float*)d_in[13];
  const float* bihf  = (const float*)d_in[14];
  const float* bhhf  = (const float*)d_in[15];
  const float* Wihb  = (const float*)d_in[16];
  const float* Whhb  = (const float*)d_in[17];
  const float* bihb  = (const float*)d_in[18];
  const float* bhhb  = (const float*)d_in[19];
  float* out = (float*)d_out;

  char* ws = (char*)d_ws;
  const size_t MT = (size_t)B_ * T_;                       // 8192
  u16* h      = (u16*)(ws);                                // 16.8 MB
  u16* xfb    = (u16*)(ws + 16777216);                     // 25.2 MB
  u16* ao     = (u16*)(ws + 41943040);                     // 16.8 MB
  u16* qkv    = (u16*)(ws + 58720256);                     // 50.3 MB (gx overlays)
  float* gx   = (float*)qkv;                               // fp32 [MT][1536], same size
  u16* WtranT = (u16*)(ws + 109051904);                    // 1.6 MB
  u16* WqkvT  = (u16*)(ws + 110624768);                    // 12.6 MB (2 layers x [3072][1024])
  u16* WoT    = (u16*)(ws + 123207680);                    // 4.2 MB
  u16* WihCat = (u16*)(ws + 127401984);                    // 3.1 MB  [1536][1024]
  _Float16* WhhFh = (_Float16*)(ws + 130547712);           // 0.4 MB
  _Float16* WhhBh = WhhFh + (size_t)768*256;
  float* qkvB  = (float*)(ws + 131334144);                 // 2 x 3072
  float* bihCat= (float*)(ws + 131358720);                 // 1536
  int* lens    = (int*)(ws + 131364864);

  // --- prep ---
  k_conv_x<<<8192, 320, 0, stream>>>(x, h, xfb);
  k_transpose_bf16<<<dim3(8, 24), 256, 0, stream>>>(Wtran, WtranT, 1536, 512);
  for (int l = 0; l < 2; ++l){
    size_t wo = (size_t)l * D_ * D_;
    size_t qo = (size_t)l * 3 * D_ * D_;
    k_transpose_bf16<<<dim3(16,16), 256, 0, stream>>>(Wq + wo, WqkvT + qo,               D_, D_);
    k_transpose_bf16<<<dim3(16,16), 256, 0, stream>>>(Wk + wo, WqkvT + qo + (size_t)D_*D_,   D_, D_);
    k_transpose_bf16<<<dim3(16,16), 256, 0, stream>>>(Wv + wo, WqkvT + qo + (size_t)2*D_*D_, D_, D_);
    k_transpose_bf16<<<dim3(16,16), 256, 0, stream>>>(Wo + wo, WoT + wo, D_, D_);
    k_copy_f32<<<4, 256, 0, stream>>>(bq + l*D_, qkvB + l*3072,        D_);
    k_copy_f32<<<4, 256, 0, stream>>>(bk + l*D_, qkvB + l*3072 + 1024, D_);
    k_copy_f32<<<4, 256, 0, stream>>>(bv + l*D_, qkvB + l*3072 + 2048, D_);
  }
  {
    int n = 768*1024;
    k_f32_to_bf16<<<(n+255)/256, 256, 0, stream>>>(Wihf, WihCat, n);
    k_f32_to_bf16<<<(n+255)/256, 256, 0, stream>>>(Wihb, WihCat + (size_t)768*1024, n);
    int m = 768*256;
    k_f32_to_f16<<<(m+255)/256, 256, 0, stream>>>(Whhf, WhhFh, m);
    k_f32_to_f16<<<(m+255)/256, 256, 0, stream>>>(Whhb, WhhBh, m);
    k_copy_f32<<<3, 256, 0, stream>>>(bihf, bihCat,       768);
    k_copy_f32<<<3, 256, 0, stream>>>(bihb, bihCat + 768, 768);
  }
  k_lengths<<<32, 256, 0, stream>>>(mask, lens);

  // --- 2 transformer layers ---
  for (int l = 0; l < 2; ++l){
    size_t qo = (size_t)l * 3 * D_ * D_;
    size_t wo = (size_t)l * D_ * D_;
    // fused QKV: [8192,1024] @ [3072,1024]^T -> bf16 [8192,3072]
    k_gemm<1><<<dim3(24,64), 256, 0, stream>>>(h, D_, WqkvT + qo, qkvB + l*3072,
                                               nullptr, qkv, D_, 3072);
    k_attn<<<16384, 256, 0, stream>>>(qkv, ao);
    // O-proj + residual (bf16): h = h + ao @ Wo^T + bo
    k_gemm<2><<<dim3(8,64), 256, 0, stream>>>(ao, D_, WoT + wo, bo + l*D_,
                                              h, h, D_, D_);
  }

  // --- GRU input GEMM (both dirs fused): gx[MT][1536] fp32 ---
  k_gemm<0><<<dim3(12,64), 256, 0, stream>>>(h, D_, WihCat, bihCat,
                                             nullptr, gx, D_, 1536);
  k_gru<<<64, 512, 0, stream>>>(WhhFh, WhhBh, bhhf, bhhb, gx, lens, out);

  // --- final: d_out += x[:, :, 1024:] @ W_tran + b_tran ---
  k_gemm<3><<<dim3(4,64), 256, 0, stream>>>(xfb, 1536, WtranT, btran,
                                            out, out, 1536, 512);
}